// Round 2
// baseline (355.522 us; speedup 1.0000x reference)
//
#include <hip/hip_runtime.h>

// Weighted BCE mean-reduction, N = 33,554,432 fp32 + int32 labels.
// History: R1/R2 ~106 us (2.4 TB/s, plain loads: L1 MSHR cap ~24 lines/CU).
// R4: nt loads bypass L1 -> ~78 us (3.44 TB/s). R5: widening MLP 4->8 pairs
// null => not outstanding-INSTRUCTION-bound. R6: global_load_lds DMA (no
// VGPR return) also ~3.44 => cap is the per-CU outstanding-LINE tracker
// (~40 lines x 128 B / 900 cy = 13.4 GB/s/CU = 3.44 TB/s device).
// R7 (this): shorten the latency the tracker must cover. Prefetch next
// iter's lines into L2 with no-return global_atomic_cmpswap (write-class,
// fire-and-forget -- the path fills sustain 6.85 TB/s on). Compare value is
// impossible (x<1.0 => bits<0x3F800000, cmp=0x40000000; y in {0,1}, cmp=2)
// and src==cmp, so memory is NEVER modified; line lands CLEAN in L2.
// Consuming nt loads then hit L2 (~200 cy): same tracker depth supports
// ~4.8x BW. One cmpswap per 128 B line, 16 active lanes/wave/iter, PD=1
// (2 MiB/iter/XCD vs 4 MiB L2; nt consume = evict-first frees lines).

#define WBCE_BLOCK 256
#define WBCE_GRID  2048            // 256 CUs x 8 blocks/CU = 32 waves/CU (max)
#define WBCE_STRIDE (WBCE_GRID * WBCE_BLOCK)   // 524288 threads
#define WBCE_ITERS 16              // n4 / WBCE_STRIDE when N = 33554432

typedef float fx4 __attribute__((ext_vector_type(4)));
typedef int   ix4 __attribute__((ext_vector_type(4)));
typedef unsigned int ux2 __attribute__((ext_vector_type(2)));

__device__ __forceinline__ float wbce_elem(float x, int y, float lw0, float lw1) {
    // returns w * ln(t) with lw = w*ln2 pre-folded: lw_sel * log2(t)
    float t  = (y == 1) ? x : (1.0f - x);
    float lw = (y == 1) ? lw1 : lw0;
    return lw * __log2f(t);
}

__device__ __forceinline__ float wbce_quad(fx4 xv, ix4 yv, float lw0, float lw1) {
    float a = wbce_elem(xv.x, yv.x, lw0, lw1);
    float b = wbce_elem(xv.y, yv.y, lw0, lw1);
    float c = wbce_elem(xv.z, yv.z, lw0, lw1);
    float d = wbce_elem(xv.w, yv.w, lw0, lw1);
    return (a + b) + (c + d);
}

__global__ __launch_bounds__(WBCE_BLOCK) void weightedBCE_75582834475452_kernel(
    const fx4* __restrict__ x4,
    const ix4* __restrict__ y4,
    const float* __restrict__ weights,
    float*       __restrict__ out,
    int n4, int n, float inv_n)
{
    const float ln2 = 0.69314718055994530942f;
    const float lw0 = weights[0] * ln2;
    const float lw1 = weights[1] * ln2;

    float acc = 0.0f;  // accumulates w * ln(t); final loss = -acc
    const int tid  = blockIdx.x * WBCE_BLOCK + threadIdx.x;
    const int lane = threadIdx.x & 63;

    if (n4 == WBCE_ITERS * WBCE_STRIDE) {
        // Flat 16-iter loop; same element->thread mapping and accumulation
        // order as R5/R6 => bit-identical sum (absmax must stay 0.0).
        #pragma unroll
        for (int i = 0; i < WBCE_ITERS; ++i) {
            const int base = tid + i * WBCE_STRIDE;
            fx4 xq = __builtin_nontemporal_load(&x4[base]);
            ix4 yq = __builtin_nontemporal_load(&y4[base]);

            // L2 prefetch of iter i+1 via no-return failed-cmpswap.
            // Wave's chunk per array per iter = 64 lanes x 16 B = 1 KiB
            // contiguous = 8 x 128 B lines. Lanes 0-7 -> x lines,
            // lanes 8-15 -> y lines (per-lane 64-bit addresses, one instr).
            if (i + 1 < WBCE_ITERS && lane < 16) {
                const size_t boff =
                    ((size_t)(tid - lane) + (size_t)(i + 1) * WBCE_STRIDE) * 16u;
                const char* p = (lane < 8)
                    ? ((const char*)x4 + boff + (size_t)lane * 128u)
                    : ((const char*)y4 + boff + (size_t)(lane - 8) * 128u);
                const unsigned cmpv = (lane < 8) ? 0x40000000u : 2u;
                ux2 dc; dc.x = cmpv; dc.y = cmpv;   // src == cmp: never writes
                // no sc0 => no return data (fire-and-forget, write-class);
                // no memory clobber needed: operation provably never stores.
                asm volatile("global_atomic_cmpswap %0, %1, off"
                             :: "v"(p), "v"(dc));
            }

            acc += wbce_quad(xq, yq, lw0, lw1);
        }
    } else {
        // Generic fallback (grid-stride) — correctness for any N.
        for (int i = tid; i < n4; i += WBCE_STRIDE) {
            fx4 xv = __builtin_nontemporal_load(&x4[i]);
            ix4 yv = __builtin_nontemporal_load(&y4[i]);
            acc += wbce_quad(xv, yv, lw0, lw1);
        }
        const float* xs = (const float*)x4;
        const int*   ys = (const int*)y4;
        for (int i = n4 * 4 + tid; i < n; i += WBCE_STRIDE) {
            acc += wbce_elem(xs[i], ys[i], lw0, lw1);
        }
    }

    // wave-64 butterfly reduce
    #pragma unroll
    for (int off = 32; off > 0; off >>= 1)
        acc += __shfl_down(acc, off, 64);

    __shared__ float smem[WBCE_BLOCK / 64];
    const int wave = threadIdx.x >> 6;
    if (lane == 0) smem[wave] = acc;
    __syncthreads();

    if (threadIdx.x == 0) {
        float total = 0.0f;
        #pragma unroll
        for (int w = 0; w < WBCE_BLOCK / 64; ++w) total += smem[w];
        // loss = -sum(w*ln t); pre-scale by 1/N so d_out holds the mean
        atomicAdd(out, -total * inv_n);
    }
}

extern "C" void kernel_launch(void* const* d_in, const int* in_sizes, int n_in,
                              void* d_out, int out_size, void* d_ws, size_t ws_size,
                              hipStream_t stream) {
    const float* x = (const float*)d_in[0];
    const int*   y = (const int*)d_in[1];
    const float* w = (const float*)d_in[2];
    float* out = (float*)d_out;
    const int n  = in_sizes[0];
    const int n4 = n >> 2;

    // d_out is poisoned to 0xAA before every timed replay — zero it on-stream
    // (hipMemsetAsync is graph-capture safe).
    (void)hipMemsetAsync(out, 0, sizeof(float), stream);

    weightedBCE_75582834475452_kernel<<<WBCE_GRID, WBCE_BLOCK, 0, stream>>>(
        (const fx4*)x, (const ix4*)y, w, out, n4, n, 1.0f / (float)n);
}

// Round 4
// 265.630 us; speedup vs baseline: 1.3384x; 1.3384x over previous
//
#include <hip/hip_runtime.h>

// Weighted BCE mean-reduction, N = 33,554,432 fp32 + int32 labels.
// History: R1/R2 ~106 us (plain loads 2.4 TB/s; L1/TCP fill path). R4: nt
// loads bypass L1 -> ~78 us kernel (3.44 TB/s). R5: 2x MLP null => not
// outstanding-count-bound. R6: global_load_lds DMA (no VGPR return) also
// 3.44 => not the VGPR return path; cap = bypass-request tracker (~40
// lines/CU in flight by Little's law). R7: L2 prefetch via no-return
// cmpswap REGRESSED (atomics wrote 120 MiB back + serialized TCC; 1.6
// TB/s). R8: sc0 inline-asm loads -> device abort; asm dropped.
// R9 (this): plain (2.4 TB/s, L1-fill-path-limited) and nt (3.44 TB/s,
// bypass-tracker-limited) were each measured ALONE. If the two structures
// are independent, driving both concurrently sums them (up to ~5.8 TB/s).
// Split: 7 of 16 iterations (0.44 ~= optimal 2.4/5.84) use plain
// L1-allocating loads, 9 use nt bypass loads, interleaved. Same element->
// thread map + accumulation order => bit-identical (absmax 0.0).

#define WBCE_BLOCK 256
#define WBCE_GRID  2048            // 256 CUs x 8 blocks/CU = 32 waves/CU (max)
#define WBCE_STRIDE (WBCE_GRID * WBCE_BLOCK)   // 524288 threads
#define WBCE_ITERS 16              // n4 / WBCE_STRIDE when N = 33554432

// Iterations routed to the plain (L1-allocating) path: {0,3,5,7,10,12,14}
#define WBCE_PLAIN_MASK 0x54A9u

typedef float fx4 __attribute__((ext_vector_type(4)));
typedef int   ix4 __attribute__((ext_vector_type(4)));

__device__ __forceinline__ float wbce_elem(float x, int y, float lw0, float lw1) {
    // returns w * ln(t) with lw = w*ln2 pre-folded: lw_sel * log2(t)
    float t  = (y == 1) ? x : (1.0f - x);
    float lw = (y == 1) ? lw1 : lw0;
    return lw * __log2f(t);
}

__device__ __forceinline__ float wbce_quad(fx4 xv, ix4 yv, float lw0, float lw1) {
    float a = wbce_elem(xv.x, yv.x, lw0, lw1);
    float b = wbce_elem(xv.y, yv.y, lw0, lw1);
    float c = wbce_elem(xv.z, yv.z, lw0, lw1);
    float d = wbce_elem(xv.w, yv.w, lw0, lw1);
    return (a + b) + (c + d);
}

__global__ __launch_bounds__(WBCE_BLOCK) void weightedBCE_75582834475452_kernel(
    const fx4* __restrict__ x4,
    const ix4* __restrict__ y4,
    const float* __restrict__ weights,
    float*       __restrict__ out,
    int n4, int n, float inv_n)
{
    const float ln2 = 0.69314718055994530942f;
    const float lw0 = weights[0] * ln2;
    const float lw1 = weights[1] * ln2;

    float acc = 0.0f;  // accumulates w * ln(t); final loss = -acc
    const int tid = blockIdx.x * WBCE_BLOCK + threadIdx.x;

    if (n4 == WBCE_ITERS * WBCE_STRIDE) {
        // R5 grouping (4 groups x 4 load-pairs in flight); per-iteration
        // path choice is compile-time (fully unrolled -> no divergence,
        // no scratch). Both memory paths stay busy across the 32 waves/CU.
        #pragma unroll
        for (int g = 0; g < WBCE_ITERS / 4; ++g) {
            fx4 xs[4]; ix4 ys[4];
            #pragma unroll
            for (int j = 0; j < 4; ++j) {
                const int it  = g * 4 + j;
                const int idx = tid + it * WBCE_STRIDE;
                if ((WBCE_PLAIN_MASK >> it) & 1u) {
                    xs[j] = x4[idx];                              // L1-fill path
                    ys[j] = y4[idx];
                } else {
                    xs[j] = __builtin_nontemporal_load(&x4[idx]); // bypass path
                    ys[j] = __builtin_nontemporal_load(&y4[idx]);
                }
            }
            #pragma unroll
            for (int j = 0; j < 4; ++j)
                acc += wbce_quad(xs[j], ys[j], lw0, lw1);
        }
    } else {
        // Generic fallback (grid-stride) — correctness for any N.
        for (int i = tid; i < n4; i += WBCE_STRIDE) {
            fx4 xv = __builtin_nontemporal_load(&x4[i]);
            ix4 yv = __builtin_nontemporal_load(&y4[i]);
            acc += wbce_quad(xv, yv, lw0, lw1);
        }
        const float* xs = (const float*)x4;
        const int*   ys = (const int*)y4;
        for (int i = n4 * 4 + tid; i < n; i += WBCE_STRIDE) {
            acc += wbce_elem(xs[i], ys[i], lw0, lw1);
        }
    }

    // wave-64 butterfly reduce
    #pragma unroll
    for (int off = 32; off > 0; off >>= 1)
        acc += __shfl_down(acc, off, 64);

    __shared__ float smem[WBCE_BLOCK / 64];
    const int lane = threadIdx.x & 63;
    const int wave = threadIdx.x >> 6;
    if (lane == 0) smem[wave] = acc;
    __syncthreads();

    if (threadIdx.x == 0) {
        float total = 0.0f;
        #pragma unroll
        for (int w = 0; w < WBCE_BLOCK / 64; ++w) total += smem[w];
        // loss = -sum(w*ln t); pre-scale by 1/N so d_out holds the mean
        atomicAdd(out, -total * inv_n);
    }
}

extern "C" void kernel_launch(void* const* d_in, const int* in_sizes, int n_in,
                              void* d_out, int out_size, void* d_ws, size_t ws_size,
                              hipStream_t stream) {
    const float* x = (const float*)d_in[0];
    const int*   y = (const int*)d_in[1];
    const float* w = (const float*)d_in[2];
    float* out = (float*)d_out;
    const int n  = in_sizes[0];
    const int n4 = n >> 2;

    // d_out is poisoned to 0xAA before every timed replay — zero it on-stream
    // (hipMemsetAsync is graph-capture safe).
    (void)hipMemsetAsync(out, 0, sizeof(float), stream);

    weightedBCE_75582834475452_kernel<<<WBCE_GRID, WBCE_BLOCK, 0, stream>>>(
        (const fx4*)x, (const ix4*)y, w, out, n4, n, 1.0f / (float)n);
}

// Round 5
// 257.815 us; speedup vs baseline: 1.3790x; 1.0303x over previous
//
#include <hip/hip_runtime.h>

// Weighted BCE mean-reduction, N = 33,554,432 fp32 + int32 labels.
// FINAL (revert to R5 best). Mechanism ledger for the read path, all at
// max occupancy (2048x256 = 32 waves/CU), full MLP, dwordx4 coalesced:
//   R1/R2 plain loads (L1-allocate)        2.40 TB/s  (L1/TCP fill path)
//   R4    nt loads -> VGPR                 3.44 TB/s  <- best
//   R5    nt, 2x per-wave MLP              3.44 (null: not count-bound)
//   R6    global_load_lds DMA (no return)  3.44 (null: not return-path)
//   R7    atomic L2-prefetch               1.62 (120 MiB writeback; revert)
//   R8    sc0 inline-asm                   device abort; asm dropped
//   R9    plain+nt mixture                 weighted avg (null: shared
//                                          downstream service point)
// Cross-check: harness fills WRITE at 6.85 TB/s; m13 float4 copy = 6.29
// aggregate (~3.15 read concurrent). Model: gfx950 streaming-read service
// caps at ~3.4 TB/s (~half the write rate) for every request class.
// Kernel floor = 268.4 MB / 3.44 TB/s = ~78 us, which this kernel hits.
// Remaining dur_us (~180 us) is harness fills + gaps, not kernel-controllable.

#define WBCE_BLOCK 256
#define WBCE_GRID  2048            // 256 CUs x 8 blocks/CU = 32 waves/CU (max)
#define WBCE_STRIDE (WBCE_GRID * WBCE_BLOCK)   // 524288 threads
#define WBCE_ITERS 16              // n4 / WBCE_STRIDE when N = 33554432

typedef float fx4 __attribute__((ext_vector_type(4)));
typedef int   ix4 __attribute__((ext_vector_type(4)));

__device__ __forceinline__ float wbce_elem(float x, int y, float lw0, float lw1) {
    // returns w * ln(t) with lw = w*ln2 pre-folded: lw_sel * log2(t)
    float t  = (y == 1) ? x : (1.0f - x);
    float lw = (y == 1) ? lw1 : lw0;
    return lw * __log2f(t);
}

__device__ __forceinline__ float wbce_quad(fx4 xv, ix4 yv, float lw0, float lw1) {
    float a = wbce_elem(xv.x, yv.x, lw0, lw1);
    float b = wbce_elem(xv.y, yv.y, lw0, lw1);
    float c = wbce_elem(xv.z, yv.z, lw0, lw1);
    float d = wbce_elem(xv.w, yv.w, lw0, lw1);
    return (a + b) + (c + d);
}

__global__ __launch_bounds__(WBCE_BLOCK) void weightedBCE_75582834475452_kernel(
    const fx4* __restrict__ x4,
    const ix4* __restrict__ y4,
    const float* __restrict__ weights,
    float*       __restrict__ out,
    int n4, int n, float inv_n)
{
    const float ln2 = 0.69314718055994530942f;
    const float lw0 = weights[0] * ln2;
    const float lw1 = weights[1] * ln2;

    float acc = 0.0f;  // accumulates w * ln(t); final loss = -acc
    const int tid = blockIdx.x * WBCE_BLOCK + threadIdx.x;

    if (n4 == WBCE_ITERS * WBCE_STRIDE) {
        // 4 groups x 4 pairs: 8 nt loads (128 B/lane) in flight per group.
        // Payload = 32 VGPRs; total stays <= 64 so 8 waves/SIMD hold.
        #pragma unroll
        for (int g = 0; g < WBCE_ITERS / 4; ++g) {
            const int base = tid + g * 4 * WBCE_STRIDE;
            fx4 xa = __builtin_nontemporal_load(&x4[base + 0 * WBCE_STRIDE]);
            fx4 xb = __builtin_nontemporal_load(&x4[base + 1 * WBCE_STRIDE]);
            fx4 xc = __builtin_nontemporal_load(&x4[base + 2 * WBCE_STRIDE]);
            fx4 xd = __builtin_nontemporal_load(&x4[base + 3 * WBCE_STRIDE]);
            ix4 ya = __builtin_nontemporal_load(&y4[base + 0 * WBCE_STRIDE]);
            ix4 yb = __builtin_nontemporal_load(&y4[base + 1 * WBCE_STRIDE]);
            ix4 yc = __builtin_nontemporal_load(&y4[base + 2 * WBCE_STRIDE]);
            ix4 yd = __builtin_nontemporal_load(&y4[base + 3 * WBCE_STRIDE]);
            acc += wbce_quad(xa, ya, lw0, lw1);
            acc += wbce_quad(xb, yb, lw0, lw1);
            acc += wbce_quad(xc, yc, lw0, lw1);
            acc += wbce_quad(xd, yd, lw0, lw1);
        }
    } else {
        // Generic fallback (grid-stride) — correctness for any N.
        for (int i = tid; i < n4; i += WBCE_STRIDE) {
            fx4 xv = __builtin_nontemporal_load(&x4[i]);
            ix4 yv = __builtin_nontemporal_load(&y4[i]);
            acc += wbce_quad(xv, yv, lw0, lw1);
        }
        const float* xs = (const float*)x4;
        const int*   ys = (const int*)y4;
        for (int i = n4 * 4 + tid; i < n; i += WBCE_STRIDE) {
            acc += wbce_elem(xs[i], ys[i], lw0, lw1);
        }
    }

    // wave-64 butterfly reduce
    #pragma unroll
    for (int off = 32; off > 0; off >>= 1)
        acc += __shfl_down(acc, off, 64);

    __shared__ float smem[WBCE_BLOCK / 64];
    const int lane = threadIdx.x & 63;
    const int wave = threadIdx.x >> 6;
    if (lane == 0) smem[wave] = acc;
    __syncthreads();

    if (threadIdx.x == 0) {
        float total = 0.0f;
        #pragma unroll
        for (int w = 0; w < WBCE_BLOCK / 64; ++w) total += smem[w];
        // loss = -sum(w*ln t); pre-scale by 1/N so d_out holds the mean
        atomicAdd(out, -total * inv_n);
    }
}

extern "C" void kernel_launch(void* const* d_in, const int* in_sizes, int n_in,
                              void* d_out, int out_size, void* d_ws, size_t ws_size,
                              hipStream_t stream) {
    const float* x = (const float*)d_in[0];
    const int*   y = (const int*)d_in[1];
    const float* w = (const float*)d_in[2];
    float* out = (float*)d_out;
    const int n  = in_sizes[0];
    const int n4 = n >> 2;

    // d_out is poisoned to 0xAA before every timed replay — zero it on-stream
    // (hipMemsetAsync is graph-capture safe).
    (void)hipMemsetAsync(out, 0, sizeof(float), stream);

    weightedBCE_75582834475452_kernel<<<WBCE_GRID, WBCE_BLOCK, 0, stream>>>(
        (const fx4*)x, (const ix4*)y, w, out, n4, n, 1.0f / (float)n);
}